// Round 11
// baseline (39.534 us; speedup 1.0000x reference)
//
#include <hip/hip_runtime.h>

#define BB 16
#define NN 65536
#define KK 64
#define TPB 1024
#define E   2048                 // output elements per block (2 per thread)
#define NBLK ((BB * NN) / E)     // 512 blocks = 2/CU -> 32 waves/CU
#define W   16384                // circular LDS window, floats (64 KB)

__device__ __forceinline__ float readlane_f(float v, int lane) {
    return __uint_as_float((unsigned)__builtin_amdgcn_readlane((int)__float_as_uint(v), lane));
}

__global__ __launch_bounds__(TPB) void frac_deriv_kernel(
    const float* __restrict__ x,
    const float* __restrict__ loc,
    const float* __restrict__ scale,
    const float* __restrict__ eps,
    const int* __restrict__ lags,
    float* __restrict__ out)
{
    __shared__ float win[W];          // circular input window
    __shared__ int   js_raw[KK];
    __shared__ float ws_raw[KK];
    __shared__ int   js[KK];          // sorted ascending
    __shared__ float ws[KK];

    const int tid  = threadIdx.x;
    const int lane = tid & 63;

    // Bijective XCD swizzle (512 blocks -> 64/XCD = 4 rows) + heavy-first.
    const int bid = blockIdx.x;
    const int swz = (bid & 7) * (NBLK / 8) + (bid >> 3);
    const int b   = swz >> 5;            // row [0,16)   (32 blocks/row)
    const int q   = 31 - (swz & 31);     // heavy-first within XCD chunk
    const int T   = q * E;

    const float* __restrict__ xr = x + (size_t)b * NN;
    const float xt0 = xr[T + tid];         // own outputs: T+tid, T+TPB+tid
    const float xt1 = xr[T + TPB + tid];

    // --- Prologue: first 64 threads compute f64 weights and rank-sort lags.
    if (tid < KK) {
        double s  = (double)scale[0];
        double sp = (s > 20.0) ? s : log1p(exp(s));
        double a  = (double)loc[0] + sp * (double)eps[0];
        a = fmin(fmax(a, 0.01), 0.99);
        double c = a * exp(-lgamma(1.0 - a)) * ((double)(NN - 1) / (double)KK);
        int j = lags[tid];
        j = (j < 1) ? 1 : ((j > NN - 1) ? NN - 1 : j);
        js_raw[tid] = j;
        ws_raw[tid] = (float)(c * exp(-(a + 1.0) * log((double)j)));
    }
    __syncthreads();
    if (tid < KK) {
        const int j = js_raw[tid];
        int rank = 0;
        for (int k = 0; k < KK; ++k) {
            const int jk = js_raw[k];
            rank += (int)((jk < j) || (jk == j && k < tid));
        }
        js[rank] = j;
        ws[rank] = ws_raw[tid];
    }
    __syncthreads();

    const int   jv = js[lane];            // identical content in every wave
    const float wv = ws[lane];
    const int cf = __popcll(__ballot(jv <= T));             // fully-valid prefix
    const int cp = __popcll(__ballot(jv <= T + (E - 1)));   // incl. straddle

    double acc0 = 0.0, acc1 = 0.0;

    // --- LDS sliding-window path over fully-valid lags, DESCENDING j.
    //     Window invariant: live region is [hi - W, hi); batch span <= W - 8.
    int m_hi = cf - 1;
    int hi   = -(1 << 30);
    while (m_hi >= 0) {
        const int J0 = __builtin_amdgcn_readlane(jv, m_hi);   // largest lag in batch
        const int s0 = T - J0;                                // leftmost needed elem
        int m_lo = m_hi;
        while (m_lo > 0) {                                    // greedy extend (uniform)
            const int Jn = __builtin_amdgcn_readlane(jv, m_lo - 1);
            if (J0 - Jn + E > W - 8) break;
            --m_lo;
        }
        const int J1      = __builtin_amdgcn_readlane(jv, m_lo);
        const int need_hi = T - J1 + E;
        const int a       = (s0 > hi) ? s0 : hi;

        __syncthreads();   // prior batch's reads complete before overwrite
        {   // stage [a, need_hi) into circular window: peel to 16B, bulk dwordx4
            const int a4 = (a + 3) & ~3;
            const int b4 = need_hi & ~3;
            if (tid < a4 - a && a + tid < need_hi)
                win[(a + tid) & (W - 1)] = xr[a + tid];
            for (int i = a4 + 4 * tid; i + 4 <= need_hi; i += 4 * TPB) {
                float4 v;
                __builtin_memcpy(&v, xr + i, 16);             // aligned dwordx4
                *(float4*)&win[i & (W - 1)] = v;              // i%4==0: no wrap in quad
            }
            if (b4 >= a4 && tid < need_hi - b4)
                win[(b4 + tid) & (W - 1)] = xr[b4 + tid];
        }
        hi = need_hi;
        __syncthreads();   // staged data visible

        // consume batch: conflict-free stride-1 ds_read_b32, groups of 8 -> f64
        float g0 = 0.f, g1 = 0.f;
        int cnt = 0;
        for (int m = m_hi; m >= m_lo; --m) {
            const int   jj = __builtin_amdgcn_readlane(jv, m);
            const float wm = readlane_f(wv, m);
            const int base = T + tid - jj;                    // >= 0 (j <= T)
            g0 = fmaf(xt0 - win[ base        & (W - 1)], wm, g0);
            g1 = fmaf(xt1 - win[(base + TPB) & (W - 1)], wm, g1);
            if (++cnt == 8) {
                acc0 += (double)g0; acc1 += (double)g1;
                g0 = g1 = 0.f; cnt = 0;
            }
        }
        acc0 += (double)g0;
        acc1 += (double)g1;
        m_hi = m_lo - 1;
    }

    // --- Straddle lags (T < j <= T+E-1): global masked path (~0-2 lags).
    for (int m = cf; m < cp; ++m) {
        const int   jj = __builtin_amdgcn_readlane(jv, m);
        const float wm = readlane_f(wv, m);
        const int d0 = T + tid - jj;
        const int d1 = d0 + TPB;
        const float p0 = xr[(d0 < 0) ? 0 : d0];
        const float p1 = xr[(d1 < 0) ? 0 : d1];
        acc0 += (d0 >= 0) ? (double)((xt0 - p0) * wm) : 0.0;
        acc1 += (d1 >= 0) ? (double)((xt1 - p1) * wm) : 0.0;
    }

    float* __restrict__ orow = out + (size_t)b * NN;
    orow[T + tid]       = (float)acc0;
    orow[T + TPB + tid] = (float)acc1;
}

extern "C" void kernel_launch(void* const* d_in, const int* in_sizes, int n_in,
                              void* d_out, int out_size, void* d_ws, size_t ws_size,
                              hipStream_t stream) {
    const float* x     = (const float*)d_in[0];
    const float* loc   = (const float*)d_in[1];
    const float* scale = (const float*)d_in[2];
    const float* eps   = (const float*)d_in[3];
    const int*   lags  = (const int*)d_in[4];
    float* out = (float*)d_out;

    frac_deriv_kernel<<<NBLK, TPB, 0, stream>>>(x, loc, scale, eps, lags, out);
}

// Round 12
// 19.286 us; speedup vs baseline: 2.0499x; 2.0499x over previous
//
#include <hip/hip_runtime.h>

#define BB 16
#define NN 65536
#define KK 64
#define TPB 1024
#define ESEG 2048                 // elements per segment (2 per thread, float2)
#define NPAIR 16                  // segment pairs per row (32 segments total)
#define NBLK (BB * NPAIR)         // 256 blocks = 1 block/CU

__device__ __forceinline__ float readlane_f(float v, int lane) {
    return __uint_as_float((unsigned)__builtin_amdgcn_readlane((int)__float_as_uint(v), lane));
}

__device__ __forceinline__ float2 load2(const float* p) {
    float2 v;
    __builtin_memcpy(&v, p, 8);    // global_load_dwordx2, align-4 ok
    return v;
}

__global__ __launch_bounds__(TPB) void frac_deriv_kernel(
    const float* __restrict__ x,
    const float* __restrict__ loc,
    const float* __restrict__ scale,
    const float* __restrict__ eps,
    const int* __restrict__ lags,
    float* __restrict__ out)
{
    __shared__ int   js_raw[KK];
    __shared__ float ws_raw[KK];
    __shared__ int   js[KK];      // sorted ascending
    __shared__ float ws[KK];

    const int tid  = threadIdx.x;
    const int lane = tid & 63;

    // Bijective XCD swizzle: 256 blocks -> 32/XCD = 2 rows per XCD L2.
    const int bid = blockIdx.x;
    const int swz = (bid & 7) * (NBLK / 8) + (bid >> 3);
    const int b   = swz >> 4;          // row [0,16)
    const int p   = swz & 15;          // pair index
    const int TA  = p * ESEG;          // light segment
    const int TB  = (31 - p) * ESEG;   // heavy segment (complementary work)

    const float* __restrict__ xr = x + (size_t)b * NN;
    const int eA = TA + 2 * tid;
    const int eB = TB + 2 * tid;
    const float2 xtA = load2(xr + eA);  // early issue
    const float2 xtB = load2(xr + eB);

    // --- Prologue: wave 0 computes f64 weights, rank-sorts lags.
    if (tid < KK) {
        double s  = (double)scale[0];
        double sp = (s > 20.0) ? s : log1p(exp(s));
        double a  = (double)loc[0] + sp * (double)eps[0];
        a = fmin(fmax(a, 0.01), 0.99);
        double c = a * exp(-lgamma(1.0 - a)) * ((double)(NN - 1) / (double)KK);
        int j = lags[tid];
        j = (j < 1) ? 1 : ((j > NN - 1) ? NN - 1 : j);
        js_raw[tid] = j;
        ws_raw[tid] = (float)(c * exp(-(a + 1.0) * log((double)j)));
    }
    __syncthreads();
    if (tid < KK) {
        const int j = js_raw[tid];
        int rank = 0;
        for (int k = 0; k < KK; ++k) {
            const int jk = js_raw[k];
            rank += (int)((jk < j) || (jk == j && k < tid));
        }
        js[rank] = j;
        ws[rank] = ws_raw[tid];
    }
    __syncthreads();

    const int   jv = js[lane];         // identical in every wave
    const float wv = ws[lane];
    const int cfA = __popcll(__ballot(jv <= TA));
    const int cpA = __popcll(__ballot(jv <= TA + (ESEG - 1)));
    const int cfB = __popcll(__ballot(jv <= TB));
    const int cpB = __popcll(__ballot(jv <= TB + (ESEG - 1)));

    double aA0 = 0.0, aA1 = 0.0, aB0 = 0.0, aB1 = 0.0;

    // --- Lockstep gather loop: 4-lag groups, raw s_barrier (no drain) paces all
    //     16 waves through the same ~20KB sliding window -> L1-resident reuse.
#define SEGLOOP(CF, E, XT, A0, A1)                                            \
    {                                                                         \
        const int cf4 = (CF) & ~3;                                            \
        for (int mo = 0; mo < cf4; mo += 4) {                                 \
            float2 u[4];                                                      \
            _Pragma("unroll")                                                 \
            for (int mi = 0; mi < 4; ++mi) {                                  \
                const int jj = __builtin_amdgcn_readlane(jv, mo + mi);        \
                u[mi] = load2(xr + ((E) - jj));                               \
            }                                                                 \
            float g0 = 0.f, g1 = 0.f;                                         \
            _Pragma("unroll")                                                 \
            for (int mi = 0; mi < 4; ++mi) {                                  \
                const float wm = readlane_f(wv, mo + mi);                     \
                g0 = fmaf((XT).x - u[mi].x, wm, g0);                          \
                g1 = fmaf((XT).y - u[mi].y, wm, g1);                          \
            }                                                                 \
            A0 += (double)g0;                                                 \
            A1 += (double)g1;                                                 \
            __builtin_amdgcn_s_barrier();  /* lockstep, loads may stay in flight */ \
        }                                                                     \
        for (int m = cf4; m < (CF); ++m) {                                    \
            const int   jj = __builtin_amdgcn_readlane(jv, m);                \
            const float wm = readlane_f(wv, m);                               \
            const float2 u = load2(xr + ((E) - jj));                          \
            A0 += (double)(((XT).x - u.x) * wm);                              \
            A1 += (double)(((XT).y - u.y) * wm);                              \
        }                                                                     \
    }

    SEGLOOP(cfA, eA, xtA, aA0, aA1)
    SEGLOOP(cfB, eB, xtB, aB0, aB1)

    // --- Straddle lags: per-element masked clamp (few lags per segment).
    for (int m = cfA; m < cpA; ++m) {
        const int   jj = __builtin_amdgcn_readlane(jv, m);
        const float wm = readlane_f(wv, m);
        const int d0 = eA - jj, d1 = d0 + 1;
        const float u0 = xr[(d0 < 0) ? 0 : d0];
        const float u1 = xr[(d1 < 0) ? 0 : d1];
        aA0 += (d0 >= 0) ? (double)((xtA.x - u0) * wm) : 0.0;
        aA1 += (d1 >= 0) ? (double)((xtA.y - u1) * wm) : 0.0;
    }
    for (int m = cfB; m < cpB; ++m) {
        const int   jj = __builtin_amdgcn_readlane(jv, m);
        const float wm = readlane_f(wv, m);
        const int d0 = eB - jj, d1 = d0 + 1;
        const float u0 = xr[(d0 < 0) ? 0 : d0];
        const float u1 = xr[(d1 < 0) ? 0 : d1];
        aB0 += (d0 >= 0) ? (double)((xtB.x - u0) * wm) : 0.0;
        aB1 += (d1 >= 0) ? (double)((xtB.y - u1) * wm) : 0.0;
    }

    float* __restrict__ orow = out + (size_t)b * NN;
    float2 rA = make_float2((float)aA0, (float)aA1);
    float2 rB = make_float2((float)aB0, (float)aB1);
    __builtin_memcpy(orow + eA, &rA, 8);
    __builtin_memcpy(orow + eB, &rB, 8);
}

extern "C" void kernel_launch(void* const* d_in, const int* in_sizes, int n_in,
                              void* d_out, int out_size, void* d_ws, size_t ws_size,
                              hipStream_t stream) {
    const float* x     = (const float*)d_in[0];
    const float* loc   = (const float*)d_in[1];
    const float* scale = (const float*)d_in[2];
    const float* eps   = (const float*)d_in[3];
    const int*   lags  = (const int*)d_in[4];
    float* out = (float*)d_out;

    frac_deriv_kernel<<<NBLK, TPB, 0, stream>>>(x, loc, scale, eps, lags, out);
}

// Round 13
// 16.909 us; speedup vs baseline: 2.3380x; 1.1406x over previous
//
#include <hip/hip_runtime.h>

#define BB 16
#define NN 65536
#define KK 64
#define TPB 256
#define EPB 1024                  // 4 elems/thread (one float4 of outputs)
#define NBLK ((BB * NN) / EPB)    // 1024 blocks = 4/CU, 16 waves/CU

__device__ __forceinline__ float readlane_f(float v, int lane) {
    return __uint_as_float((unsigned)__builtin_amdgcn_readlane((int)__float_as_uint(v), lane));
}

// Non-temporal gather of 4 consecutive floats (4B-aligned: natural alignment).
// nt bit: no L1 allocation for streaming misses that will never be re-read.
__device__ __forceinline__ float4 load4_nt(const float* p) {
    float4 v;
    v.x = __builtin_nontemporal_load(p);
    v.y = __builtin_nontemporal_load(p + 1);
    v.z = __builtin_nontemporal_load(p + 2);
    v.w = __builtin_nontemporal_load(p + 3);
    return v;
}

__global__ __launch_bounds__(TPB) void frac_deriv_kernel(
    const float* __restrict__ x,
    const float* __restrict__ loc,
    const float* __restrict__ scale,
    const float* __restrict__ eps,
    const int* __restrict__ lags,
    float* __restrict__ out)
{
    __shared__ int   js_raw[KK];
    __shared__ float ws_raw[KK];
    __shared__ int   js[KK];
    __shared__ float ws[KK];

    const int tid  = threadIdx.x;
    const int lane = tid & 63;

    // Bijective XCD swizzle (128 blocks/XCD = 2 rows) + heavy-first within XCD.
    const int bid = blockIdx.x;
    const int swz = (bid & 7) * (NBLK / 8) + (bid >> 3);
    const int b   = swz >> 6;
    const int q   = 63 - (swz & 63);     // heavy-first
    const int T   = q * EPB;

    const float* __restrict__ xr = x + (size_t)b * NN;
    const int e0 = T + 4 * tid;
    float4 xt;
    __builtin_memcpy(&xt, xr + e0, 16);  // normal (cached) load, issued early

    // --- Prologue: wave 0 computes f64 weights and rank-sorts lags.
    if (tid < KK) {
        double s  = (double)scale[0];
        double sp = (s > 20.0) ? s : log1p(exp(s));
        double a  = (double)loc[0] + sp * (double)eps[0];
        a = fmin(fmax(a, 0.01), 0.99);
        double c = a * exp(-lgamma(1.0 - a)) * ((double)(NN - 1) / (double)KK);
        int j = lags[tid];
        j = (j < 1) ? 1 : ((j > NN - 1) ? NN - 1 : j);
        js_raw[tid] = j;
        ws_raw[tid] = (float)(c * exp(-(a + 1.0) * log((double)j)));
    }
    __syncthreads();
    if (tid < KK) {
        const int j = js_raw[tid];
        int rank = 0;
        for (int k = 0; k < KK; ++k) {
            const int jk = js_raw[k];
            rank += (int)((jk < j) || (jk == j && k < tid));
        }
        js[rank] = j;
        ws[rank] = ws_raw[tid];
    }
    __syncthreads();

    const int   jv = js[lane];
    const float wv = ws[lane];
    const int cf = __popcll(__ballot(jv <= T));             // fully-valid prefix
    const int cp = __popcll(__ballot(jv <= T + (EPB - 1))); // incl. straddle
    const int cf8 = cf & ~7;

    double a0 = 0.0, a1 = 0.0, a2 = 0.0, a3 = 0.0;

    // --- Fully-valid lags: 8-lag groups; NT gathers (no L1 allocation).
    for (int mo = 0; mo < cf8; mo += 8) {
        float4 g = make_float4(0.f, 0.f, 0.f, 0.f);
#pragma unroll
        for (int mi = 0; mi < 8; ++mi) {
            const int   m  = mo + mi;
            const int   jj = __builtin_amdgcn_readlane(jv, m);
            const float w  = readlane_f(wv, m);
            const float4 xg = load4_nt(xr + (e0 - jj));
            g.x = fmaf(xt.x - xg.x, w, g.x);
            g.y = fmaf(xt.y - xg.y, w, g.y);
            g.z = fmaf(xt.z - xg.z, w, g.z);
            g.w = fmaf(xt.w - xg.w, w, g.w);
        }
        a0 += (double)g.x; a1 += (double)g.y; a2 += (double)g.z; a3 += (double)g.w;
    }
    // Remainder of fully-valid lags.
    for (int m = cf8; m < cf; ++m) {
        const int   jj = __builtin_amdgcn_readlane(jv, m);
        const float w  = readlane_f(wv, m);
        const float4 xg = load4_nt(xr + (e0 - jj));
        a0 += (double)((xt.x - xg.x) * w);
        a1 += (double)((xt.y - xg.y) * w);
        a2 += (double)((xt.z - xg.z) * w);
        a3 += (double)((xt.w - xg.w) * w);
    }
    // Straddle lags: per-element masked clamp (~1 lag typical).
    for (int m = cf; m < cp; ++m) {
        const int   jj = __builtin_amdgcn_readlane(jv, m);
        const float w  = readlane_f(wv, m);
        const int d0 = e0 - jj;
        const float g0 = xr[(d0     < 0) ? 0 : d0];
        const float g1 = xr[(d0 + 1 < 0) ? 0 : d0 + 1];
        const float g2 = xr[(d0 + 2 < 0) ? 0 : d0 + 2];
        const float g3 = xr[(d0 + 3 < 0) ? 0 : d0 + 3];
        a0 += (d0     >= 0) ? (double)((xt.x - g0) * w) : 0.0;
        a1 += (d0 + 1 >= 0) ? (double)((xt.y - g1) * w) : 0.0;
        a2 += (d0 + 2 >= 0) ? (double)((xt.z - g2) * w) : 0.0;
        a3 += (d0 + 3 >= 0) ? (double)((xt.w - g3) * w) : 0.0;
    }

    float4 r = make_float4((float)a0, (float)a1, (float)a2, (float)a3);
    __builtin_memcpy(out + (size_t)b * NN + e0, &r, 16);
}

extern "C" void kernel_launch(void* const* d_in, const int* in_sizes, int n_in,
                              void* d_out, int out_size, void* d_ws, size_t ws_size,
                              hipStream_t stream) {
    const float* x     = (const float*)d_in[0];
    const float* loc   = (const float*)d_in[1];
    const float* scale = (const float*)d_in[2];
    const float* eps   = (const float*)d_in[3];
    const int*   lags  = (const int*)d_in[4];
    float* out = (float*)d_out;

    frac_deriv_kernel<<<NBLK, TPB, 0, stream>>>(x, loc, scale, eps, lags, out);
}